// Round 9
// baseline (344.516 us; speedup 1.0000x reference)
//
#include <hip/hip_runtime.h>
#include <hip/hip_bf16.h>

// Problem constants (match reference file)
constexpr int K    = 8192;
constexpr int N4   = 6144;    // int4 rows
constexpr int N8   = 2048;    // uint8 rows
constexpr int NT   = N4 + N8; // 8192 output columns
constexpr int NG   = K / 128; // 64 groups per int4 row

typedef short  short8  __attribute__((ext_vector_type(8)));
typedef float  floatx4 __attribute__((ext_vector_type(4)));

__device__ inline short f2bf(float f) {
    __hip_bfloat16 h = __float2bfloat16(f);   // RNE
    return __builtin_bit_cast(short, h);
}

// ---------------------------------------------------------------------------
// Prep: x2bf = bf16(x/awq) stored in MFMA A-fragment order:
//   x2bf[c*512 + lane*8 + j] = X[m = lane&15][k = c*32 + (lane>>4)*8 + j]
// Also: fwd = inverse of inv_perm.
// ---------------------------------------------------------------------------
__global__ void prep_kernel(const float* __restrict__ x,
                            const float* __restrict__ awq,
                            const int*   __restrict__ inv_perm,
                            short* __restrict__ x2bf,
                            int*   __restrict__ fwd) {
    const int tid  = blockIdx.x * blockDim.x + threadIdx.x;   // 0..131071
    const int c    = tid >> 9;
    const int rem  = tid & 511;
    const int lane = rem >> 3;
    const int j    = rem & 7;
    const int m    = lane & 15;
    const int k    = c * 32 + (lane >> 4) * 8 + j;
    x2bf[tid] = f2bf(x[m * K + k] / awq[k]);
    if (tid < NT) fwd[inv_perm[tid]] = tid;
}

// ---------------------------------------------------------------------------
// MFMA dot-chunk, deferred scale: B = bf16(w + off), off = -8 (int4) or -128
// (uint8 nibble merge; exact in bf16). Group scale applied on 64-k partials.
// ---------------------------------------------------------------------------
__device__ __forceinline__ floatx4 chunk_mfma(int4 wa, int4 wb, short8 xv,
                                              float off, floatx4 cin) {
    short8 bf;
    bf[0] = f2bf((float)wa.x + off);
    bf[1] = f2bf((float)wa.y + off);
    bf[2] = f2bf((float)wa.z + off);
    bf[3] = f2bf((float)wa.w + off);
    bf[4] = f2bf((float)wb.x + off);
    bf[5] = f2bf((float)wb.y + off);
    bf[6] = f2bf((float)wb.z + off);
    bf[7] = f2bf((float)wb.w + off);
    return __builtin_amdgcn_mfma_f32_16x16x32_bf16(xv, bf, cin, 0, 0, 0);
}

// ---------------------------------------------------------------------------
// Register-pipelined MFMA GEMV, 3-deep ring.  Block = 4 waves (256 thr) = one
// 16-row tile; wave w owns k in [w*2048, (w+1)*2048) as 32 stages of 64 k.
//
// __launch_bounds__(256, 2) is the point of this round: it grants a 256-VGPR
// budget (2 waves/EU floor).  Without it the compiler targeted 8 waves/SIMD
// (<=64 VGPR) and SANK every load to its use, collapsing the pipeline to
// ~1.5 loads in flight (VGPR_Count 36/48 in R4/R6 -> 2.7 TB/s ceiling).
// Grid = 512 blocks = 2 blocks/CU, so >=2 waves/EU costs nothing.
//
//   int4 rows : acc += s4[row,g] * (sum_k x[m,k]*(w-8))
//   uint8 rows: acc += s8[row]   * (sum_k x[m,k]*(w-128))   (nibble merge)
// Epilogue: 4-way LDS reduce + single permuted/biased store per element.
// ---------------------------------------------------------------------------
__global__ __launch_bounds__(256, 2)
void qgemv_kernel(const short* __restrict__ xf,
                  const int*   __restrict__ w4,
                  const float* __restrict__ s4,
                  const int*   __restrict__ w8,
                  const float* __restrict__ s8,
                  const int*   __restrict__ fwd,
                  const float* __restrict__ bias,
                  float* __restrict__ out) {
    __shared__ float red[4][256];

    const int t    = threadIdx.x;
    const int lane = t & 63;
    const int w    = t >> 6;            // wave 0..3
    const int nb   = blockIdx.x * 16;   // tile base row (type uniform)
    const int i    = lane & 15;
    const int q    = lane >> 4;
    const int row  = nb + i;

    const bool  is4 = (nb < N4);
    const float off = is4 ? -8.f : -128.f;

    const int*   wp = (is4 ? (w4 + (size_t)row * K)
                           : (w8 + (size_t)(row - N4) * K)) + w * 2048 + q * 8;
    const short* xw = xf + (size_t)w * 64 * 512 + lane * 8;
    const float* sp = s4 + (size_t)row * NG + w * 16;
    const float  s8row = is4 ? 0.f : s8[row - N4];

    floatx4 acc = {0.f, 0.f, 0.f, 0.f};

    int4   wA0, wA1, wA2, wA3, wB0, wB1, wB2, wB3, wC0, wC1, wC2, wC3;
    short8 xA0, xA1, xB0, xB1, xC0, xC1;
    float  sA, sB, sC;

#define LOADSTAGE(S, W0, W1, W2, W3, X0, X1, SS)                     \
    do {                                                             \
        const int c_ = 2 * (S);                                      \
        W0 = *(const int4*)(wp + (size_t)c_ * 32);                   \
        W1 = *(const int4*)(wp + (size_t)c_ * 32 + 4);               \
        W2 = *(const int4*)(wp + (size_t)c_ * 32 + 32);              \
        W3 = *(const int4*)(wp + (size_t)c_ * 32 + 36);              \
        X0 = *(const short8*)(xw + (size_t)c_ * 512);                \
        X1 = *(const short8*)(xw + (size_t)c_ * 512 + 512);          \
        SS = is4 ? sp[(S) >> 1] : s8row;                             \
    } while (0)

#define COMPSTAGE(W0, W1, W2, W3, X0, X1, SS)                        \
    do {                                                             \
        floatx4 g_ = chunk_mfma(W0, W1, X0, off,                     \
                                (floatx4){0.f, 0.f, 0.f, 0.f});      \
        g_ = chunk_mfma(W2, W3, X1, off, g_);                        \
        acc[0] += (SS) * g_[0];                                      \
        acc[1] += (SS) * g_[1];                                      \
        acc[2] += (SS) * g_[2];                                      \
        acc[3] += (SS) * g_[3];                                      \
    } while (0)

    // Prologue: 3 stages in flight.
    LOADSTAGE(0, wA0, wA1, wA2, wA3, xA0, xA1, sA);
    LOADSTAGE(1, wB0, wB1, wB2, wB3, xB0, xB1, sB);
    LOADSTAGE(2, wC0, wC1, wC2, wC3, xC0, xC1, sC);

    // Steady state: 27 stages in 9 triples; loads cover stages 3..29.
    #pragma unroll 1
    for (int s = 0; s < 27; s += 3) {
        COMPSTAGE(wA0, wA1, wA2, wA3, xA0, xA1, sA);
        LOADSTAGE(s + 3, wA0, wA1, wA2, wA3, xA0, xA1, sA);
        COMPSTAGE(wB0, wB1, wB2, wB3, xB0, xB1, sB);
        LOADSTAGE(s + 4, wB0, wB1, wB2, wB3, xB0, xB1, sB);
        COMPSTAGE(wC0, wC1, wC2, wC3, xC0, xC1, sC);
        LOADSTAGE(s + 5, wC0, wC1, wC2, wC3, xC0, xC1, sC);
    }
    // Epilogue of the pipeline: stages 27..31 (loads 30, 31 only).
    COMPSTAGE(wA0, wA1, wA2, wA3, xA0, xA1, sA);
    LOADSTAGE(30, wA0, wA1, wA2, wA3, xA0, xA1, sA);
    COMPSTAGE(wB0, wB1, wB2, wB3, xB0, xB1, sB);
    LOADSTAGE(31, wB0, wB1, wB2, wB3, xB0, xB1, sB);
    COMPSTAGE(wC0, wC1, wC2, wC3, xC0, xC1, sC);
    COMPSTAGE(wA0, wA1, wA2, wA3, xA0, xA1, sA);
    COMPSTAGE(wB0, wB1, wB2, wB3, xB0, xB1, sB);

#undef LOADSTAGE
#undef COMPSTAGE

    // ---- 4-way cross-wave reduce + fused perm/bias writeout ----
    #pragma unroll
    for (int r = 0; r < 4; ++r)
        red[w][(q * 4 + r) * 16 + i] = acc[r];
    __syncthreads();

    if (t < 256) {
        const float v = red[0][t] + red[1][t] + red[2][t] + red[3][t];
        const int m  = t >> 4;     // batch row
        const int i2 = t & 15;     // tile col
        const int n  = nb + i2;
        const int d  = fwd[n];
        out[(size_t)m * NT + d] = v + bias[d];
    }
}

// ---------------------------------------------------------------------------
extern "C" void kernel_launch(void* const* d_in, const int* in_sizes, int n_in,
                              void* d_out, int out_size, void* d_ws, size_t ws_size,
                              hipStream_t stream) {
    const float* x        = (const float*)d_in[0];
    const int*   w_int4   = (const int*)  d_in[1];
    const float* s_int4   = (const float*)d_in[2];
    const int*   w_uint8  = (const int*)  d_in[3];
    const float* s_int8   = (const float*)d_in[4];
    const float* awq      = (const float*)d_in[5];
    const float* bias     = (const float*)d_in[6];
    const int*   inv_perm = (const int*)  d_in[7];
    // d_in[8] = group_size (==128), compile-time constant here

    short* x2bf = (short*)d_ws;                                        // 256 KB
    int*   fwd  = (int*)((char*)d_ws + (size_t)16 * K * sizeof(short)); // 32 KB

    prep_kernel<<<(16 * K) / 256, 256, 0, stream>>>(x, awq, inv_perm, x2bf, fwd);
    qgemv_kernel<<<NT / 16, 256, 0, stream>>>(x2bf, w_int4, s_int4,
                                              w_uint8, s_int8, fwd, bias,
                                              (float*)d_out);
}

// Round 10
// 343.478 us; speedup vs baseline: 1.0030x; 1.0030x over previous
//
#include <hip/hip_runtime.h>
#include <hip/hip_bf16.h>

// Problem constants (match reference file)
constexpr int K    = 8192;
constexpr int N4   = 6144;    // int4 rows
constexpr int N8   = 2048;    // uint8 rows
constexpr int NT   = N4 + N8; // 8192 output columns
constexpr int NG   = K / 128; // 64 groups per int4 row

typedef short  short8  __attribute__((ext_vector_type(8)));
typedef float  floatx4 __attribute__((ext_vector_type(4)));

__device__ __forceinline__ short f2bf(float f) {
    __hip_bfloat16 h = __float2bfloat16(f);   // RNE
    return __builtin_bit_cast(short, h);
}
// bf16 by truncation: EXACT for integer-valued f with |f| <= 255 (<=8 mantissa bits)
__device__ __forceinline__ short ibf(float f) {
    return (short)(__builtin_bit_cast(unsigned, f) >> 16);
}

// ---------------------------------------------------------------------------
// Prep: x2bf = bf16(x/awq) in MFMA A-fragment order:
//   x2bf[c*512 + lane*8 + j] = X[m = lane&15][k = c*32 + (lane>>4)*8 + j]
// fwd = inverse of inv_perm.
// ---------------------------------------------------------------------------
__global__ void prep_kernel(const float* __restrict__ x,
                            const float* __restrict__ awq,
                            const int*   __restrict__ inv_perm,
                            short* __restrict__ x2bf,
                            int*   __restrict__ fwd) {
    const int tid  = blockIdx.x * blockDim.x + threadIdx.x;   // 0..131071
    const int c    = tid >> 9;
    const int rem  = tid & 511;
    const int lane = rem >> 3;
    const int j    = rem & 7;
    const int m    = lane & 15;
    const int k    = c * 32 + (lane >> 4) * 8 + j;
    x2bf[tid] = f2bf(x[m * K + k] / awq[k]);
    if (tid < NT) fwd[inv_perm[tid]] = tid;
}

// ---------------------------------------------------------------------------
// repack4: w_int4 (int32 per 4-bit value, 201 MB) -> packed nibbles in MFMA
// B-fragment order (25 MB):
//   p4[tile*16384 + c*64 + q*16 + i]  holds k = c*32 + q*8 + 0..7 (nibble j)
//   of row tile*16 + i.
// Reads are SEQUENTIAL per wave (m13 pattern); LDS transpose makes each
// block's 1 KB output write fully contiguous.
// ---------------------------------------------------------------------------
__global__ __launch_bounds__(256)
void repack4_kernel(const int* __restrict__ w4, unsigned* __restrict__ p4) {
    __shared__ unsigned lt[16][17];
    const int j    = threadIdx.x;
    const int tile = blockIdx.x >> 6;     // 0..383
    const int gb   = blockIdx.x & 63;     // 16-octet group within tile
    const int rl   = j >> 4;              // row-local 0..15
    const int kl   = j & 15;              // octet-local 0..15
    const size_t t_in = (size_t)(tile * 16 + rl) * 1024 + gb * 16 + kl;
    const int4 a = *(const int4*)(w4 + t_in * 8);
    const int4 b = *(const int4*)(w4 + t_in * 8 + 4);
    lt[rl][kl] = (unsigned)(a.x & 15)        | ((unsigned)(a.y & 15) << 4)
               | ((unsigned)(a.z & 15) << 8) | ((unsigned)(a.w & 15) << 12)
               | ((unsigned)(b.x & 15) << 16)| ((unsigned)(b.y & 15) << 20)
               | ((unsigned)(b.z & 15) << 24)| ((unsigned)(b.w & 15) << 28);
    __syncthreads();
    const int cL = j >> 6, rem = j & 63, q = rem >> 4, i = rem & 15;
    p4[(size_t)tile * 16384 + gb * 256 + j] = lt[i][cL * 4 + q];
}

// ---------------------------------------------------------------------------
// repack8: w_uint8 (int32 per byte, 67 MB) -> packed bytes in fragment order
// (17 MB):  p8[tile8*16384 + c*64 + q*16 + i] (uint2) holds k = c*32 + q*8
// + 0..7 of row tile8*16 + i.
// ---------------------------------------------------------------------------
__global__ __launch_bounds__(256)
void repack8_kernel(const int* __restrict__ w8, uint2* __restrict__ p8) {
    __shared__ uint2 lt[16][17];
    const int j    = threadIdx.x;
    const int tile = blockIdx.x >> 6;     // 0..127
    const int gb   = blockIdx.x & 63;
    const int rl   = j >> 4;
    const int kl   = j & 15;
    const size_t t_in = (size_t)(tile * 16 + rl) * 1024 + gb * 16 + kl;
    const int4 a = *(const int4*)(w8 + t_in * 8);
    const int4 b = *(const int4*)(w8 + t_in * 8 + 4);
    uint2 d;
    d.x = (unsigned)(a.x & 255)         | ((unsigned)(a.y & 255) << 8)
        | ((unsigned)(a.z & 255) << 16) | ((unsigned)(a.w & 255) << 24);
    d.y = (unsigned)(b.x & 255)         | ((unsigned)(b.y & 255) << 8)
        | ((unsigned)(b.z & 255) << 16) | ((unsigned)(b.w & 255) << 24);
    lt[rl][kl] = d;
    __syncthreads();
    const int cL = j >> 6, rem = j & 63, q = rem >> 4, i = rem & 15;
    p8[(size_t)tile * 16384 + gb * 256 + j] = lt[i][cL * 4 + q];
}

// ---------------------------------------------------------------------------
// Dequant to EXACT-integer bf16 fragments (deferred f32 scale).
// ---------------------------------------------------------------------------
__device__ __forceinline__ short8 dq4(unsigned v) {
    short8 r;
    #pragma unroll
    for (int j = 0; j < 8; ++j)
        r[j] = ibf((float)((v >> (4 * j)) & 15u) - 8.f);
    return r;
}
__device__ __forceinline__ short8 dq8(uint2 d) {
    short8 r;
    #pragma unroll
    for (int j = 0; j < 4; ++j) {
        r[j]     = ibf((float)((d.x >> (8 * j)) & 255u) - 128.f);
        r[4 + j] = ibf((float)((d.y >> (8 * j)) & 255u) - 128.f);
    }
    return r;
}

// ---------------------------------------------------------------------------
// MFMA GEMV on packed weights. Block = 4 waves = one 16-row tile; wave w =
// k-split [w*2048, w*2048+2048) = 64 chunks of 32 k. Weight load per chunk:
// ONE dword/lane (int4) or dwordx2 (uint8), contiguous 256/512 B per
// instruction (fragment-ordered by repack). Weight stream is 42 MB total
// (6.4x smaller than raw); x-frags (256 KB) stay L2-resident.
//   int4 rows : acc += s4[row,g] * (sum_k x[m,k]*(w-8))
//   uint8 rows: acc += s8[row]   * (sum_k x[m,k]*(w-128))   (nibble merge)
// Epilogue: 4-way LDS reduce over splits + fused perm/bias store.
// ---------------------------------------------------------------------------
__global__ __launch_bounds__(256)
void qgemv_kernel(const short* __restrict__ xf,
                  const unsigned* __restrict__ p4,
                  const float* __restrict__ s4,
                  const uint2* __restrict__ p8,
                  const float* __restrict__ s8,
                  const int*   __restrict__ fwd,
                  const float* __restrict__ bias,
                  float* __restrict__ out) {
    __shared__ float red[4][256];

    const int t    = threadIdx.x;
    const int lane = t & 63;
    const int w    = t >> 6;            // wave = k-split 0..3
    const int tile = blockIdx.x;        // 0..511
    const int nb   = tile * 16;
    const int i    = lane & 15;
    const int q    = lane >> 4;
    const int row  = nb + i;

    floatx4 acc = {0.f, 0.f, 0.f, 0.f};

    if (nb < N4) {
        const unsigned* pw = p4 + (size_t)tile * 16384;
        const float*    sp = s4 + (size_t)row * NG;
        #pragma unroll 1
        for (int cg = 0; cg < 16; ++cg) {       // one 128-k scale group
            const int c0 = w * 64 + cg * 4;
            floatx4 g = {0.f, 0.f, 0.f, 0.f};
            #pragma unroll
            for (int cc = 0; cc < 4; ++cc) {
                const int c = c0 + cc;
                const unsigned v  = pw[(size_t)c * 64 + lane];
                const short8   xv = *(const short8*)(xf + (size_t)c * 512 + lane * 8);
                g = __builtin_amdgcn_mfma_f32_16x16x32_bf16(xv, dq4(v), g, 0, 0, 0);
            }
            const float sg = sp[c0 >> 2];
            acc[0] += sg * g[0]; acc[1] += sg * g[1];
            acc[2] += sg * g[2]; acc[3] += sg * g[3];
        }
    } else {
        const uint2* pw  = p8 + (size_t)(tile - N4 / 16) * 16384;
        const float  s8r = s8[row - N4];
        #pragma unroll 1
        for (int cg = 0; cg < 16; ++cg) {
            const int c0 = w * 64 + cg * 4;
            floatx4 g = {0.f, 0.f, 0.f, 0.f};
            #pragma unroll
            for (int cc = 0; cc < 4; ++cc) {
                const int c = c0 + cc;
                const uint2  v  = pw[(size_t)c * 64 + lane];
                const short8 xv = *(const short8*)(xf + (size_t)c * 512 + lane * 8);
                g = __builtin_amdgcn_mfma_f32_16x16x32_bf16(xv, dq8(v), g, 0, 0, 0);
            }
            acc[0] += s8r * g[0]; acc[1] += s8r * g[1];
            acc[2] += s8r * g[2]; acc[3] += s8r * g[3];
        }
    }

    // ---- 4-way cross-split reduce + fused perm/bias writeout ----
    #pragma unroll
    for (int r = 0; r < 4; ++r)
        red[w][(q * 4 + r) * 16 + i] = acc[r];
    __syncthreads();

    if (t < 256) {
        const float v = red[0][t] + red[1][t] + red[2][t] + red[3][t];
        const int m  = t >> 4;     // batch row
        const int i2 = t & 15;     // tile col
        const int n  = nb + i2;
        const int d  = fwd[n];
        out[(size_t)m * NT + d] = v + bias[d];
    }
}

// ---------------------------------------------------------------------------
extern "C" void kernel_launch(void* const* d_in, const int* in_sizes, int n_in,
                              void* d_out, int out_size, void* d_ws, size_t ws_size,
                              hipStream_t stream) {
    const float* x        = (const float*)d_in[0];
    const int*   w_int4   = (const int*)  d_in[1];
    const float* s_int4   = (const float*)d_in[2];
    const int*   w_uint8  = (const int*)  d_in[3];
    const float* s_int8   = (const float*)d_in[4];
    const float* awq      = (const float*)d_in[5];
    const float* bias     = (const float*)d_in[6];
    const int*   inv_perm = (const int*)  d_in[7];
    // d_in[8] = group_size (==128), compile-time constant here

    char* ws = (char*)d_ws;
    short*    x2bf = (short*)ws;                         // 262144 B
    int*      fwd  = (int*)(ws + 262144);                //  32768 B
    unsigned* p4   = (unsigned*)(ws + 294912);           // 25165824 B
    uint2*    p8   = (uint2*)(ws + 294912 + 25165824);   // 16777216 B

    prep_kernel<<<512, 256, 0, stream>>>(x, awq, inv_perm, x2bf, fwd);
    repack4_kernel<<<24576, 256, 0, stream>>>(w_int4, p4);
    repack8_kernel<<<8192, 256, 0, stream>>>(w_uint8, p8);
    qgemv_kernel<<<512, 256, 0, stream>>>(x2bf, p4, s_int4, p8, s_int8,
                                          fwd, bias, (float*)d_out);
}